// Round 15
// baseline (548.267 us; speedup 1.0000x reference)
//
#include <hip/hip_runtime.h>
#include <math.h>

#define BB 2
#define NN 8192
#define KK 16
#define DIMM 64
#define HH 32
#define NBB 5
#define RESS 64
#define NPTS (BB*NN)            // 16384
#define PLANE_ELEMS (BB*3*RESS*RESS*DIMM)   // 1572864
#define PLANE_CELLS (BB*3*RESS*RESS)        // 24576
#define GC 8                    // knn grid cells per dim
#define GCS 0.125f              // cell size
#define NCELL (GC*GC*GC)        // 512 per batch
#define CAP 640                 // staged r=1 box cap (box ~Poisson(432), +10s)
#define GRP 2                   // 8-query groups per cell (stride 16)

// ---------------- zero workspace ----------------
__global__ void zero_kernel(float* __restrict__ p, int n) {
  int t = blockIdx.x * blockDim.x + threadIdx.x;
  if (t < n) p[t] = 0.0f;
}

// ---------------- stem: c = xyz @ w_stem + b_stem ; copy xyz to out ----------------
__global__ void stem_kernel(const float* __restrict__ xyz,
                            const float* __restrict__ w,
                            const float* __restrict__ bias,
                            float* __restrict__ out_xyz,
                            float* __restrict__ c) {
  int tid = blockIdx.x * blockDim.x + threadIdx.x;
  if (tid < NPTS*3) out_xyz[tid] = xyz[tid];
  if (tid < NPTS*DIMM) {
    int p = tid >> 6, d = tid & 63;
    float x = xyz[p*3+0], y = xyz[p*3+1], z = xyz[p*3+2];
    c[tid] = x*w[d] + y*w[64+d] + z*w[128+d] + bias[d];
  }
}

// ---------------- binned exact KNN ----------------
__device__ __forceinline__ unsigned ord32(float f) {
  unsigned u = __float_as_uint(f);
  return u ^ ((unsigned)((int)u >> 31) | 0x80000000u);
}
__device__ __forceinline__ int cell_of(float v) {
  return min(max((int)((v + 0.5f) * 8.0f), 0), 7);
}

__global__ void knn_count_kernel(const float* __restrict__ xyz,
                                 int* __restrict__ cellcnt) {
  int p = blockIdx.x * blockDim.x + threadIdx.x;
  if (p >= NPTS) return;
  int bq = p >> 13;
  float px = xyz[p*3], py = xyz[p*3+1], pz = xyz[p*3+2];
  int cc = (cell_of(px) << 6) | (cell_of(py) << 3) | cell_of(pz);
  atomicAdd(&cellcnt[(bq << 9) | cc], 1);
}

__global__ __launch_bounds__(1024) void knn_scan_kernel(const int* __restrict__ cnt,
                                                        int* __restrict__ cellstart,
                                                        int* __restrict__ cellcur) {
  __shared__ int s[1024];
  int t = threadIdx.x;
  int v = cnt[t];
  s[t] = v;
  __syncthreads();
  for (int off = 1; off < 1024; off <<= 1) {
    int add = (t >= off) ? s[t-off] : 0;
    __syncthreads();
    s[t] += add;
    __syncthreads();
  }
  int inc = s[t];
  cellstart[t+1] = inc;
  if (t == 0) cellstart[0] = 0;
  cellcur[t] = inc - v;      // exclusive start, used as scatter cursor
}

__global__ void knn_scatter_kernel(const float* __restrict__ xyz,
                                   int* __restrict__ cellcur,
                                   float4* __restrict__ spts) {
  int p = blockIdx.x * blockDim.x + threadIdx.x;
  if (p >= NPTS) return;
  int bq = p >> 13;
  float px = xyz[p*3], py = xyz[p*3+1], pz = xyz[p*3+2];
  int cc = (cell_of(px) << 6) | (cell_of(py) << 3) | cell_of(pz);
  int pos = atomicAdd(&cellcur[(bq << 9) | cc], 1);
  spts[pos] = make_float4(px, py, pz, __int_as_float(p & (NN-1)));
}

#define U64MIN(a,b) (((a) < (b)) ? (a) : (b))
#define U64MAX(a,b) (((a) < (b)) ? (b) : (a))

// Parallel branchless insert of u64 key into per-lane sorted bd[16]; ~0ull no-op.
#define INS64(key)                                                             \
  {                                                                            \
    unsigned long long _k = (key);                                             \
    _Pragma("unroll")                                                          \
    for (int jj = 15; jj >= 1; --jj) {                                         \
      unsigned long long up = bd[jj-1];                                        \
      bool shift = _k < up;                                                    \
      bool here  = _k < bd[jj];                                                \
      unsigned long long nv = shift ? up : _k;                                 \
      bd[jj] = here ? nv : bd[jj];                                             \
    }                                                                          \
    bd[0] = (_k < bd[0]) ? _k : bd[0];                                         \
  }

// FIFO drain: 4 sentinel-padded inserts; updates threshold.
#define DRAIN64()                                                              \
  {                                                                            \
    INS64((0 < fcnt) ? fd[0] : ~0ull);                                         \
    INS64((1 < fcnt) ? fd[1] : ~0ull);                                         \
    INS64((2 < fcnt) ? fd[2] : ~0ull);                                         \
    INS64((3 < fcnt) ? fd[3] : ~0ull);                                         \
    fcnt = 0; hi15 = (unsigned)(bd[15] >> 32);                                 \
  }

// Staged-scan step: distance + cheap per-lane FIFO push; batched drain.
// Stale hi15 between drains is only LOOSER (no misses); u64-key selection is
// order-independent so batching is exact. d2 expression identical to R6/R8.
#define TRYKEY_F(c4)                                                           \
  {                                                                            \
    float sq = (c4).x*(c4).x + (c4).y*(c4).y + (c4).z*(c4).z;                  \
    float d2 = (qs + sq) - 2.0f*(qx*(c4).x + qy*(c4).y + qz*(c4).z);           \
    unsigned du = ord32(d2);                                                   \
    bool hit = valid && du <= hi15;                                            \
    unsigned long long key =                                                   \
        ((unsigned long long)du << 32) | (unsigned)__float_as_int((c4).w);     \
    _Pragma("unroll")                                                          \
    for (int j2 = 0; j2 < 4; ++j2)                                             \
      fd[j2] = (hit && fcnt == j2) ? key : fd[j2];                             \
    fcnt += hit;                                                               \
    if (__any(fcnt >= 4)) { DRAIN64(); }                                       \
  }

// Gated immediate insert for the (rare) global fallback paths.
#define TRYKEY(c4)                                                             \
  {                                                                            \
    float sq = (c4).x*(c4).x + (c4).y*(c4).y + (c4).z*(c4).z;                  \
    float d2 = (qs + sq) - 2.0f*(qx*(c4).x + qy*(c4).y + qz*(c4).z);           \
    unsigned du = ord32(d2);                                                   \
    bool hit = valid && du <= hi15;                                            \
    if (__any(hit)) {                                                          \
      unsigned long long key = hit ?                                           \
          (((unsigned long long)du << 32) | (unsigned)__float_as_int((c4).w))  \
          : ~0ull;                                                             \
      INS64(key);                                                              \
      hi15 = (unsigned)(bd[15] >> 32);                                         \
    }                                                                          \
  }

// Bitonic merge for DISJOINT sorted lists (staged-scan slice merges: every
// candidate scanned by exactly one slice; at masks 8/16/32 the merged unions
// stay pairwise disjoint). 16 smallest of A,B = min(A[i],B[15-i]); re-sort
// bitonic result with a 4-stage network. NOT valid for ring re-merges.
#define BMERGE_STEP(MASK)                                                      \
  {                                                                            \
    unsigned long long tmp[16];                                                \
    _Pragma("unroll")                                                          \
    for (int j = 0; j < 16; ++j) tmp[j] = __shfl_xor(bd[15-j], MASK);          \
    _Pragma("unroll")                                                          \
    for (int j = 0; j < 16; ++j) bd[j] = U64MIN(bd[j], tmp[j]);                \
    _Pragma("unroll")                                                          \
    for (int dd2 = 8; dd2 >= 1; dd2 >>= 1) {                                   \
      _Pragma("unroll")                                                        \
      for (int i2 = 0; i2 < 16; ++i2) {                                        \
        if ((i2 & dd2) == 0) {                                                 \
          unsigned long long a2 = bd[i2], b2 = bd[i2 + dd2];                   \
          bd[i2] = U64MIN(a2, b2); bd[i2 + dd2] = U64MAX(a2, b2);              \
        }                                                                      \
      }                                                                        \
    }                                                                          \
    hi15 = (unsigned)(bd[15] >> 32);                                           \
  }

// Dedup butterfly merge for ring re-merges (slices share a merged base; keys
// unique per candidate -> equality-dedup exact; sentinels dedup harmlessly).
#define MERGE_STEP(MASK)                                                       \
  {                                                                            \
    unsigned long long tmp[16];                                                \
    _Pragma("unroll")                                                          \
    for (int j = 0; j < 16; ++j) tmp[j] = __shfl_xor(bd[j], MASK);             \
    _Pragma("unroll")                                                          \
    for (int j = 0; j < 16; ++j) {                                             \
      unsigned long long _in = tmp[j];                                         \
      bool dup = false;                                                        \
      _Pragma("unroll")                                                        \
      for (int jj = 0; jj < 16; ++jj) dup = dup || (bd[jj] == _in);            \
      INS64(dup ? ~0ull : _in);                                                \
    }                                                                          \
    hi15 = (unsigned)(bd[15] >> 32);                                           \
  }

// knn_query v7: 8 queries x 8 slices per wave; GRP=2 blocks per cell (block g
// takes queries 8g + 16t). Cells hold ~Poisson(16) queries so both blocks are
// active ~97% of the time (R13's 16-stride split left group1 idle half the
// time). Scan halves per block; per-lane hits halve -> fewer coherent drains.
__global__ __launch_bounds__(64) void knn_query_kernel(
    const float4* __restrict__ spts, const int* __restrict__ cellstart,
    int* __restrict__ idx) {
  __shared__ __align__(16) float4 s_cand[CAP];   // 10240 B
  __shared__ int s_ofs[28];
  __shared__ int s_jlo[27];
  int wave = blockIdx.x >> 1;       // cell id 0..1023
  int g = blockIdx.x & 1;           // query group within cell
  int b = wave >> 9;
  int cell = wave & 511;
  int cx = cell >> 6, cy = (cell >> 3) & 7, cz = cell & 7;
  int cb = b << 9;
  int qlo = cellstart[cb + cell], qhi = cellstart[cb + cell + 1];
  int nq = qhi - qlo;
  if (nq <= 0 || 8*g >= nq) return;
  int lane = threadIdx.x;
  int q = lane & 7, s = lane >> 3;  // 8 queries x 8 slices

  int x0 = max(cx-1,0), x1 = min(cx+1,7);
  int y0 = max(cy-1,0), y1 = min(cy+1,7);
  int z0 = max(cz-1,0), z1 = min(cz+1,7);
  int dy = y1-y0+1, dz = z1-z0+1;
  int count = (x1-x0+1)*dy*dz;      // 8..27
  int len = 0, jlo0 = 0;
  if (lane < count) {
    int xx = x0 + lane/(dy*dz);
    int rem = lane % (dy*dz);
    int yy = y0 + rem/dz, zz = z0 + rem % dz;
    int cc = cb + (xx<<6) + (yy<<3) + zz;
    jlo0 = cellstart[cc];
    len = cellstart[cc+1] - jlo0;
  }
  int pre = len;
#pragma unroll
  for (int off = 1; off < 64; off <<= 1) {
    int v = __shfl_up(pre, off);
    if (lane >= off) pre += v;
  }
  if (lane < count) { s_ofs[lane] = pre - len; s_jlo[lane] = jlo0; }
  if (lane == count-1) s_ofs[count] = pre;
  __syncthreads();
  int total = s_ofs[count];
  int tstag = min(total, CAP);

  for (int w = lane; w < tstag; w += 64) {
    int lo2 = 0, hi2 = count-1;
    while (lo2 < hi2) { int mid = (lo2+hi2+1)>>1; if (s_ofs[mid] <= w) lo2 = mid; else hi2 = mid-1; }
    s_cand[w] = spts[s_jlo[lo2] + (w - s_ofs[lo2])];
  }
  __syncthreads();

  const unsigned thru1 = ord32((GCS - 1e-4f)*(GCS - 1e-4f));
  for (int qg = 8*g; qg < nq; qg += 16) {
    bool valid = (qg + q) < nq;
    float4 qv = spts[qlo + qg + (valid ? q : 0)];
    float qx = qv.x, qy = qv.y, qz = qv.z;
    float qs = qx*qx + qy*qy + qz*qz;
    unsigned long long bd[16];
#pragma unroll
    for (int j = 0; j < 16; ++j) bd[j] = ~0ull;
    unsigned long long fd[4] = {0,0,0,0};
    int fcnt = 0;
    unsigned hi15 = 0xFFFFFFFFu;

    // LDS scan: slice s takes a contiguous eighth; FIFO-batched inserts
    int chunk = (tstag + 7) >> 3;
    int jb = s*chunk, je = min(jb+chunk, tstag);
    for (int j = jb; j < je; ++j) {
      float4 c4 = s_cand[j];
      TRYKEY_F(c4);
    }
    if (__any(fcnt > 0)) { DRAIN64(); }
    // overflow remainder (total > CAP; ~never): from global, gated
    if (total > CAP) {
      for (int i = 0; i < count; ++i) {
        int ofs_i = s_ofs[i], len_i = s_ofs[i+1]-ofs_i;
        int stg = min(max(CAP - ofs_i, 0), len_i);
        int jl = s_jlo[i] + stg, jh = s_jlo[i] + len_i;
        for (int j2 = jl + s; j2 < jh; j2 += 8) {
          float4 c4 = spts[j2];
          TRYKEY(c4);
        }
      }
    }
    BMERGE_STEP(8);                  // slices disjoint -> bitonic O(k) merges
    BMERGE_STEP(16);
    BMERGE_STEP(32);
    bool done = !valid || (hi15 < thru1);
    // rings r>=2 (rare): global scan; shared base -> dedup merges
    for (int r = 2; r <= 8; ++r) {
      if (!__any(!done)) break;
      int xs0 = max(cx-r,0), xs1 = min(cx+r,7);
      int ys0 = max(cy-r,0), ys1 = min(cy+r,7);
      int zs0 = max(cz-r,0), zs1 = min(cz+r,7);
      int pr = r-1;
      for (int xx = xs0; xx <= xs1; ++xx)
      for (int yy = ys0; yy <= ys1; ++yy)
      for (int zz = zs0; zz <= zs1; ++zz) {
        if (xx >= cx-pr && xx <= cx+pr && yy >= cy-pr && yy <= cy+pr &&
            zz >= cz-pr && zz <= cz+pr) continue;
        int cc2 = cb + (xx<<6) + (yy<<3) + zz;
        int jl = cellstart[cc2], jh = cellstart[cc2+1];
        for (int j2 = jl + s; j2 < jh; j2 += 8) {
          float4 c4 = spts[j2];
          TRYKEY(c4);
        }
      }
      MERGE_STEP(8);
      MERGE_STEP(16);
      MERGE_STEP(32);
      float thr2 = (float)r * GCS - 1e-4f;
      done = !valid || (hi15 < ord32(thr2*thr2));
    }
    if (valid && s == 0) {
      int n_self = __float_as_int(qv.w);
      int* op = idx + (((long)b << 13) + n_self) * 16;
#pragma unroll
      for (int j = 0; j < 16; ++j) op[j] = (int)(unsigned)(bd[j] & 0xffffffffu);
    }
  }
}

// ---------------- x = relu(c @ w0[l] + b0[l]) ----------------
__global__ void xproj_kernel(const float* __restrict__ c,
                             const float* __restrict__ w0,
                             const float* __restrict__ b0,
                             float* __restrict__ x, int layer) {
  int tid = blockIdx.x * blockDim.x + threadIdx.x;
  if (tid >= NPTS*HH) return;
  int p = tid >> 5, h = tid & 31;
  const float* w = w0 + layer*DIMM*HH;
  const float* cr = c + p*DIMM;
  float acc = b0[layer*HH + h];
#pragma unroll
  for (int d = 0; d < DIMM; ++d) acc += cr[d]*w[d*HH + h];
  x[tid] = fmaxf(acc, 0.0f);
}

// ---------------- fused FKAConv v4: 256 thr = 4 waves = 4 points ----------------
#define OFF_W1   0
#define OFF_W2AT 48        // [16][20] transposed fc2 rows 0..15
#define OFF_W2BT 368       // [16][20] transposed fc2 rows 16..31
#define OFF_W3AT 688
#define OFF_W3BT 1008
#define OFF_B2   1328      // [64]
#define OFF_RED  1392      // y partials [8 seg][4 pt][32 o]
#define OFF_Y    2416      // [4 pt][32 o]
#define OFF_SCR  2544      // per-wave scratch x4
#define SCR_SZ   1296
#define S_DW 0
#define S_M1 16
#define S_M2 272
#define S_MM 528
#define S_XN 784
#define S_FB 16            // overlays M1+M2 (dead after stage C)
#define LDS_TOT (OFF_SCR + 4*SCR_SZ)   // 7728 floats = 30912 B -> 5 blocks/CU

__global__ __launch_bounds__(256) void conv_kernel(
    float* __restrict__ c, const float* __restrict__ x,
    const int* __restrict__ idx, const float* __restrict__ xyz,
    const float* __restrict__ fc1, const float* __restrict__ fc2,
    const float* __restrict__ fc3, const float* __restrict__ wcv,
    const float* __restrict__ alpha, const float* __restrict__ beta,
    const float* __restrict__ w2, const float* __restrict__ b2, int layer)
{
  __shared__ __align__(16) float lds[LDS_TOT];
  int t = threadIdx.x;

  const float* fc1l = fc1 + layer*3*KK;
  const float* fc2l = fc2 + layer*2*KK*KK;
  const float* fc3l = fc3 + layer*2*KK*KK;
  const float* wcvl = wcv + layer*HH*HH*KK;
  const float* w2l  = w2  + layer*HH*DIMM;
  const float* b2l  = b2  + layer*DIMM;

  if (t < 48) lds[OFF_W1 + t] = fc1l[t];
  {
    int s = t >> 4, tt = t & 15;
    lds[OFF_W2AT + s*20 + tt] = fc2l[tt*16 + s];
    lds[OFF_W2BT + s*20 + tt] = fc2l[(16+tt)*16 + s];
    lds[OFF_W3AT + s*20 + tt] = fc3l[tt*16 + s];
    lds[OFF_W3BT + s*20 + tt] = fc3l[(16+tt)*16 + s];
  }
  if (t < 64) lds[OFF_B2 + t] = b2l[t];
  __syncthreads();                                  // barrier 1/4

  int wv = t >> 6, lane = t & 63;
  int p = blockIdx.x*4 + wv;
  int b = p >> 13;
  float* scr = lds + OFF_SCR + wv*SCR_SZ;
  int sI = lane & 15;

  // ---- stage A (per-wave scratch only; no block barrier) ----
  float qxx = xyz[p*3+0], qyy = xyz[p*3+1], qzz = xyz[p*3+2];
  float alv = alpha[layer], bev = beta[layer];
  int jidx = 0; float px = 0, py = 0, pz = 0, sv = 0;
  if (lane < 16) {
    jidx = idx[p*16 + lane];
    const float* nb = xyz + ((long)b*NN + jidx)*3;
    px = nb[0]-qxx; py = nb[1]-qyy; pz = nb[2]-qzz;
    float dd = sqrtf(px*px + py*py + pz*pz + 1e-12f);
    sv = 1.0f/(1.0f + expf(alv*dd - bev));
  }
  float ssum = 0.0f;
#pragma unroll
  for (int k = 0; k < 16; ++k) ssum += __shfl(sv, k);
  if (lane < 16) scr[S_DW + lane] = sv / (ssum + 1e-6f) * 16.0f;
#pragma unroll
  for (int r = 0; r < 2; ++r) {
    int tsk = lane + 64*r;
    int k = tsk >> 3, seg = tsk & 7;
    int jk = __shfl(jidx, k);
    float4 v = *(const float4*)(x + ((long)b*NN + jk)*32 + seg*4);
    *(float4*)&scr[S_XN + k*32 + seg*4] = v;
  }
#pragma unroll
  for (int r = 0; r < 4; ++r) {
    int k = (lane >> 4) + 4*r;
    float pxk = __shfl(px, k), pyk = __shfl(py, k), pzk = __shfl(pz, k);
    float v = pxk*lds[OFF_W1+sI] + pyk*lds[OFF_W1+16+sI] + pzk*lds[OFF_W1+32+sI];
    scr[S_M1 + k*16 + sI] = fmaxf(v, 0.0f);
  }

  // ---- stage B ----
  {
    float mpv = 0.0f;
#pragma unroll
    for (int k = 0; k < 16; ++k) mpv = fmaxf(mpv, scr[S_M1 + k*16 + sI] * scr[S_DW + k]);
    float qv = 0.0f;
#pragma unroll
    for (int tt = 0; tt < 16; ++tt) qv += __shfl(mpv, tt) * lds[OFF_W2BT + sI*20 + tt];
    float4 wa0 = *(float4*)&lds[OFF_W2AT + sI*20 + 0];
    float4 wa1 = *(float4*)&lds[OFF_W2AT + sI*20 + 4];
    float4 wa2 = *(float4*)&lds[OFF_W2AT + sI*20 + 8];
    float4 wa3 = *(float4*)&lds[OFF_W2AT + sI*20 + 12];
#pragma unroll
    for (int r = 0; r < 4; ++r) {
      int k = (lane >> 4) + 4*r;
      float4 m0 = *(float4*)&scr[S_M1 + k*16 + 0];
      float4 m1_ = *(float4*)&scr[S_M1 + k*16 + 4];
      float4 m2_ = *(float4*)&scr[S_M1 + k*16 + 8];
      float4 m3_ = *(float4*)&scr[S_M1 + k*16 + 12];
      float v = qv;
      v += m0.x*wa0.x; v += m0.y*wa0.y; v += m0.z*wa0.z; v += m0.w*wa0.w;
      v += m1_.x*wa1.x; v += m1_.y*wa1.y; v += m1_.z*wa1.z; v += m1_.w*wa1.w;
      v += m2_.x*wa2.x; v += m2_.y*wa2.y; v += m2_.z*wa2.z; v += m2_.w*wa2.w;
      v += m3_.x*wa3.x; v += m3_.y*wa3.y; v += m3_.z*wa3.z; v += m3_.w*wa3.w;
      scr[S_M2 + k*16 + sI] = fmaxf(v, 0.0f);
    }
  }

  // ---- stage C ----
  {
    float mpv = 0.0f;
#pragma unroll
    for (int k = 0; k < 16; ++k) mpv = fmaxf(mpv, scr[S_M2 + k*16 + sI] * scr[S_DW + k]);
    float qv = 0.0f;
#pragma unroll
    for (int tt = 0; tt < 16; ++tt) qv += __shfl(mpv, tt) * lds[OFF_W3BT + sI*20 + tt];
    float4 wa0 = *(float4*)&lds[OFF_W3AT + sI*20 + 0];
    float4 wa1 = *(float4*)&lds[OFF_W3AT + sI*20 + 4];
    float4 wa2 = *(float4*)&lds[OFF_W3AT + sI*20 + 8];
    float4 wa3 = *(float4*)&lds[OFF_W3AT + sI*20 + 12];
#pragma unroll
    for (int r = 0; r < 4; ++r) {
      int k = (lane >> 4) + 4*r;
      float4 m0 = *(float4*)&scr[S_M2 + k*16 + 0];
      float4 m1_ = *(float4*)&scr[S_M2 + k*16 + 4];
      float4 m2_ = *(float4*)&scr[S_M2 + k*16 + 8];
      float4 m3_ = *(float4*)&scr[S_M2 + k*16 + 12];
      float v = qv;
      v += m0.x*wa0.x; v += m0.y*wa0.y; v += m0.z*wa0.z; v += m0.w*wa0.w;
      v += m1_.x*wa1.x; v += m1_.y*wa1.y; v += m1_.z*wa1.z; v += m1_.w*wa1.w;
      v += m2_.x*wa2.x; v += m2_.y*wa2.y; v += m2_.z*wa2.z; v += m2_.w*wa2.w;
      v += m3_.x*wa3.x; v += m3_.y*wa3.y; v += m3_.z*wa3.z; v += m3_.w*wa3.w;
      scr[S_MM + k*16 + sI] = fmaxf(v, 0.0f) * scr[S_DW + k];
    }
  }

  // ---- stage D: f[c][s] into FB (overlays dead M1+M2) ----
  {
    int q4 = lane >> 4;
    float fr0=0,fr1=0,fr2=0,fr3=0,fr4=0,fr5=0,fr6=0,fr7=0;
#pragma unroll
    for (int k = 0; k < 16; ++k) {
      float mmv = scr[S_MM + k*16 + sI];
      float4 a  = *(float4*)&scr[S_XN + k*32 + q4*8];
      float4 bb = *(float4*)&scr[S_XN + k*32 + q4*8 + 4];
      fr0 += a.x*mmv;  fr1 += a.y*mmv;  fr2 += a.z*mmv;  fr3 += a.w*mmv;
      fr4 += bb.x*mmv; fr5 += bb.y*mmv; fr6 += bb.z*mmv; fr7 += bb.w*mmv;
    }
    scr[S_FB + (q4*8+0)*16 + sI] = fr0;
    scr[S_FB + (q4*8+1)*16 + sI] = fr1;
    scr[S_FB + (q4*8+2)*16 + sI] = fr2;
    scr[S_FB + (q4*8+3)*16 + sI] = fr3;
    scr[S_FB + (q4*8+4)*16 + sI] = fr4;
    scr[S_FB + (q4*8+5)*16 + sI] = fr5;
    scr[S_FB + (q4*8+6)*16 + sI] = fr6;
    scr[S_FB + (q4*8+7)*16 + sI] = fr7;
  }
  __syncthreads();                                  // barrier 2/4 (cross-wave FB)

  // ---- block GEMM y-einsum: thread (o, seg); wcv read once per block ----
  {
    int o = t & 31, seg = t >> 5;
    const float4* wrow = (const float4*)(wcvl + o*512 + seg*64);
    float acc0=0, acc1=0, acc2=0, acc3=0;
#pragma unroll
    for (int j = 0; j < 16; ++j) {
      float4 w4 = wrow[j];
      float4 f0 = *(const float4*)&lds[OFF_SCR + 0*SCR_SZ + S_FB + seg*64 + j*4];
      float4 f1 = *(const float4*)&lds[OFF_SCR + 1*SCR_SZ + S_FB + seg*64 + j*4];
      float4 f2 = *(const float4*)&lds[OFF_SCR + 2*SCR_SZ + S_FB + seg*64 + j*4];
      float4 f3 = *(const float4*)&lds[OFF_SCR + 3*SCR_SZ + S_FB + seg*64 + j*4];
      acc0 += w4.x*f0.x; acc0 += w4.y*f0.y; acc0 += w4.z*f0.z; acc0 += w4.w*f0.w;
      acc1 += w4.x*f1.x; acc1 += w4.y*f1.y; acc1 += w4.z*f1.z; acc1 += w4.w*f1.w;
      acc2 += w4.x*f2.x; acc2 += w4.y*f2.y; acc2 += w4.z*f2.z; acc2 += w4.w*f2.w;
      acc3 += w4.x*f3.x; acc3 += w4.y*f3.y; acc3 += w4.z*f3.z; acc3 += w4.w*f3.w;
    }
    lds[OFF_RED + seg*128 + 0*32 + o] = acc0;
    lds[OFF_RED + seg*128 + 1*32 + o] = acc1;
    lds[OFF_RED + seg*128 + 2*32 + o] = acc2;
    lds[OFF_RED + seg*128 + 3*32 + o] = acc3;
  }
  __syncthreads();                                  // barrier 3/4

  if (t < 128) {
    int pt = t >> 5, o = t & 31;
    float yv = 0.0f;
#pragma unroll
    for (int seg = 0; seg < 8; ++seg) yv += lds[OFF_RED + seg*128 + pt*32 + o];
    lds[OFF_Y + pt*32 + o] = fmaxf(yv, 0.0f);
  }
  __syncthreads();                                  // barrier 4/4

  // ---- final: c = relu(y @ w2 + b2 + c); w2 direct from global (coalesced) ----
  {
    int pt = t >> 6, d = t & 63;
    float zv = lds[OFF_B2 + d];
    const float* w2g = w2l + d;
#pragma unroll
    for (int o = 0; o < 32; ++o) zv += lds[OFF_Y + pt*32 + o] * w2g[o*64];
    int gp = blockIdx.x*4 + pt;
    float cv = c[gp*64 + d];
    c[gp*64 + d] = fmaxf(zv + cv, 0.0f);
  }
}

// ---------------- triplane scatter-accumulate ----------------
__global__ void triacc_kernel(const float* __restrict__ c,
                              const float* __restrict__ xyz,
                              float* __restrict__ psum,
                              float* __restrict__ pcnt) {
  int tid = blockIdx.x * blockDim.x + threadIdx.x;
  if (tid >= NPTS*DIMM) return;
  int p = tid >> 6, d = tid & 63;
  int b = p >> 13;
  float p0 = xyz[p*3+0] / 1.101f + 0.5f;
  float p1 = xyz[p*3+1] / 1.101f + 0.5f;
  float p2 = xyz[p*3+2] / 1.101f + 0.5f;
  int i0 = min(max((int)(p0*64.0f), 0), 63);
  int i1 = min(max((int)(p1*64.0f), 0), 63);
  int i2 = min(max((int)(p2*64.0f), 0), 63);
  int cb = b*3*RESS*RESS;
  int c0 = cb + 0*RESS*RESS + i0*RESS + i1;
  int c1 = cb + 1*RESS*RESS + i0*RESS + i2;
  int c2 = cb + 2*RESS*RESS + i1*RESS + i2;
  float v = c[tid];
  atomicAdd(&psum[c0*DIMM + d], v);
  atomicAdd(&psum[c1*DIMM + d], v);
  atomicAdd(&psum[c2*DIMM + d], v);
  if (d == 0) {
    atomicAdd(&pcnt[c0], 1.0f);
    atomicAdd(&pcnt[c1], 1.0f);
    atomicAdd(&pcnt[c2], 1.0f);
  }
}

// ---------------- triplane normalize ----------------
__global__ void trinorm_kernel(const float* __restrict__ psum,
                               const float* __restrict__ pcnt,
                               float* __restrict__ out) {
  int tid = blockIdx.x * blockDim.x + threadIdx.x;
  if (tid >= PLANE_ELEMS) return;
  float cnt = pcnt[tid >> 6];
  out[tid] = psum[tid] / fmaxf(cnt, 1.0f);
}

extern "C" void kernel_launch(void* const* d_in, const int* in_sizes, int n_in,
                              void* d_out, int out_size, void* d_ws, size_t ws_size,
                              hipStream_t stream) {
  const float* xyz   = (const float*)d_in[0];
  const float* wstem = (const float*)d_in[1];
  const float* bstem = (const float*)d_in[2];
  const float* w0    = (const float*)d_in[3];
  const float* b0    = (const float*)d_in[4];
  const float* fc1   = (const float*)d_in[5];
  const float* fc2   = (const float*)d_in[6];
  const float* fc3   = (const float*)d_in[7];
  const float* wcv   = (const float*)d_in[8];
  const float* alpha = (const float*)d_in[9];
  const float* beta  = (const float*)d_in[10];
  const float* w2    = (const float*)d_in[11];
  const float* b2    = (const float*)d_in[12];

  float* out     = (float*)d_out;
  float* out_xyz = out;                       // 49152
  float* c       = out + NPTS*3;              // working c buffer
  float* out_tri = c + NPTS*DIMM;             // 1572864

  float* wsf  = (float*)d_ws;
  int*   idx  = (int*)d_ws;                   // NPTS*16 int32
  float* x    = wsf + NPTS*16;                // NPTS*32
  float* psum = x + NPTS*HH;                  // PLANE_ELEMS
  float* pcnt = psum + PLANE_ELEMS;           // PLANE_CELLS

  // knn bin arrays ALIAS psum (dead until triplane; zeroed after knn)
  int*    cellcnt   = (int*)psum;             // 1024
  int*    cellstart = (int*)psum + 1024;      // 1025 (pad to 1032)
  int*    cellcur   = (int*)psum + 2056;      // 1024
  float4* spts      = (float4*)(psum + 4096); // 16384 float4

  stem_kernel<<<(NPTS*DIMM+255)/256, 256, 0, stream>>>(xyz, wstem, bstem, out_xyz, c);
  zero_kernel<<<4, 256, 0, stream>>>((float*)cellcnt, 1024);
  knn_count_kernel<<<(NPTS+255)/256, 256, 0, stream>>>(xyz, cellcnt);
  knn_scan_kernel<<<1, 1024, 0, stream>>>(cellcnt, cellstart, cellcur);
  knn_scatter_kernel<<<(NPTS+255)/256, 256, 0, stream>>>(xyz, cellcur, spts);
  knn_query_kernel<<<1024*GRP, 64, 0, stream>>>(spts, cellstart, idx);
  for (int layer = 0; layer < NBB; ++layer) {
    xproj_kernel<<<(NPTS*HH+255)/256, 256, 0, stream>>>(c, w0, b0, x, layer);
    conv_kernel<<<NPTS/4, 256, 0, stream>>>(c, x, idx, xyz, fc1, fc2, fc3, wcv,
                                            alpha, beta, w2, b2, layer);
  }
  int nz = PLANE_ELEMS + PLANE_CELLS;
  zero_kernel<<<(nz+255)/256, 256, 0, stream>>>(psum, nz);
  triacc_kernel<<<(NPTS*DIMM+255)/256, 256, 0, stream>>>(c, xyz, psum, pcnt);
  trinorm_kernel<<<(PLANE_ELEMS+255)/256, 256, 0, stream>>>(psum, pcnt, out_tri);
}

// Round 16
// 502.025 us; speedup vs baseline: 1.0921x; 1.0921x over previous
//
#include <hip/hip_runtime.h>
#include <math.h>

#define BB 2
#define NN 8192
#define KK 16
#define DIMM 64
#define HH 32
#define NBB 5
#define RESS 64
#define NPTS (BB*NN)            // 16384
#define PLANE_ELEMS (BB*3*RESS*RESS*DIMM)   // 1572864
#define PLANE_CELLS (BB*3*RESS*RESS)        // 24576
#define GC 8
#define GCS 0.125f
#define NCELL (GC*GC*GC)
#define CAP 640                 // staged r=1 box cap (box ~Poisson(432), +10s)
#define GRP 3                   // query-group blocks per cell (R13/R14 cfg)

// ---------------- zero workspace ----------------
__global__ void zero_kernel(float* __restrict__ p, int n) {
  int t = blockIdx.x * blockDim.x + threadIdx.x;
  if (t < n) p[t] = 0.0f;
}

// ---- stem (fused): out_xyz copy, c = xyz@wstem+bstem, x0 = relu(c@w0[0]+b0[0]),
// ---- and knn cell counts (d==0 thread). x0 recomputes c inline with the
// ---- TEXTUALLY IDENTICAL expression -> bitwise-same x0 as separate xproj.
__device__ __forceinline__ int cell_of(float v) {
  return min(max((int)((v + 0.5f) * 8.0f), 0), 7);
}

__global__ void stem_kernel(const float* __restrict__ xyz,
                            const float* __restrict__ w,
                            const float* __restrict__ bias,
                            const float* __restrict__ w0,
                            const float* __restrict__ b0,
                            float* __restrict__ out_xyz,
                            float* __restrict__ c,
                            float* __restrict__ x0,
                            int* __restrict__ cellcnt) {
  int tid = blockIdx.x * blockDim.x + threadIdx.x;
  if (tid < NPTS*3) out_xyz[tid] = xyz[tid];
  if (tid < NPTS*DIMM) {
    int p = tid >> 6, d = tid & 63;
    float x = xyz[p*3+0], y = xyz[p*3+1], z = xyz[p*3+2];
    c[tid] = x*w[d] + y*w[64+d] + z*w[128+d] + bias[d];
    if (d == 0) {
      int bq = p >> 13;
      int cc = (cell_of(x) << 6) | (cell_of(y) << 3) | cell_of(z);
      atomicAdd(&cellcnt[(bq << 9) | cc], 1);
    }
  }
  if (tid < NPTS*HH) {
    int p = tid >> 5, h = tid & 31;
    float x = xyz[p*3+0], y = xyz[p*3+1], z = xyz[p*3+2];
    float acc = b0[h];
#pragma unroll
    for (int d = 0; d < DIMM; ++d) {
      float cd = x*w[d] + y*w[64+d] + z*w[128+d] + bias[d];
      acc += cd * w0[d*HH + h];
    }
    x0[tid] = fmaxf(acc, 0.0f);
  }
}

// ---------------- binned exact KNN (R14 config — plateau) ----------------
__device__ __forceinline__ unsigned ord32(float f) {
  unsigned u = __float_as_uint(f);
  return u ^ ((unsigned)((int)u >> 31) | 0x80000000u);
}

__global__ __launch_bounds__(1024) void knn_scan_kernel(const int* __restrict__ cnt,
                                                        int* __restrict__ cellstart,
                                                        int* __restrict__ cellcur) {
  __shared__ int s[1024];
  int t = threadIdx.x;
  int v = cnt[t];
  s[t] = v;
  __syncthreads();
  for (int off = 1; off < 1024; off <<= 1) {
    int add = (t >= off) ? s[t-off] : 0;
    __syncthreads();
    s[t] += add;
    __syncthreads();
  }
  int inc = s[t];
  cellstart[t+1] = inc;
  if (t == 0) cellstart[0] = 0;
  cellcur[t] = inc - v;
}

__global__ void knn_scatter_kernel(const float* __restrict__ xyz,
                                   int* __restrict__ cellcur,
                                   float4* __restrict__ spts) {
  int p = blockIdx.x * blockDim.x + threadIdx.x;
  if (p >= NPTS) return;
  int bq = p >> 13;
  float px = xyz[p*3], py = xyz[p*3+1], pz = xyz[p*3+2];
  int cc = (cell_of(px) << 6) | (cell_of(py) << 3) | cell_of(pz);
  int pos = atomicAdd(&cellcur[(bq << 9) | cc], 1);
  spts[pos] = make_float4(px, py, pz, __int_as_float(p & (NN-1)));
}

#define U64MIN(a,b) (((a) < (b)) ? (a) : (b))
#define U64MAX(a,b) (((a) < (b)) ? (b) : (a))

#define INS64(key)                                                             \
  {                                                                            \
    unsigned long long _k = (key);                                             \
    _Pragma("unroll")                                                          \
    for (int jj = 15; jj >= 1; --jj) {                                         \
      unsigned long long up = bd[jj-1];                                        \
      bool shift = _k < up;                                                    \
      bool here  = _k < bd[jj];                                                \
      unsigned long long nv = shift ? up : _k;                                 \
      bd[jj] = here ? nv : bd[jj];                                             \
    }                                                                          \
    bd[0] = (_k < bd[0]) ? _k : bd[0];                                         \
  }

#define DRAIN64()                                                              \
  {                                                                            \
    INS64((0 < fcnt) ? fd[0] : ~0ull);                                         \
    INS64((1 < fcnt) ? fd[1] : ~0ull);                                         \
    INS64((2 < fcnt) ? fd[2] : ~0ull);                                         \
    INS64((3 < fcnt) ? fd[3] : ~0ull);                                         \
    fcnt = 0; hi15 = (unsigned)(bd[15] >> 32);                                 \
  }

#define TRYKEY_F(c4)                                                           \
  {                                                                            \
    float sq = (c4).x*(c4).x + (c4).y*(c4).y + (c4).z*(c4).z;                  \
    float d2 = (qs + sq) - 2.0f*(qx*(c4).x + qy*(c4).y + qz*(c4).z);           \
    unsigned du = ord32(d2);                                                   \
    bool hit = valid && du <= hi15;                                            \
    unsigned long long key =                                                   \
        ((unsigned long long)du << 32) | (unsigned)__float_as_int((c4).w);     \
    _Pragma("unroll")                                                          \
    for (int j2 = 0; j2 < 4; ++j2)                                             \
      fd[j2] = (hit && fcnt == j2) ? key : fd[j2];                             \
    fcnt += hit;                                                               \
    if (__any(fcnt >= 4)) { DRAIN64(); }                                       \
  }

#define TRYKEY(c4)                                                             \
  {                                                                            \
    float sq = (c4).x*(c4).x + (c4).y*(c4).y + (c4).z*(c4).z;                  \
    float d2 = (qs + sq) - 2.0f*(qx*(c4).x + qy*(c4).y + qz*(c4).z);           \
    unsigned du = ord32(d2);                                                   \
    bool hit = valid && du <= hi15;                                            \
    if (__any(hit)) {                                                          \
      unsigned long long key = hit ?                                           \
          (((unsigned long long)du << 32) | (unsigned)__float_as_int((c4).w))  \
          : ~0ull;                                                             \
      INS64(key);                                                              \
      hi15 = (unsigned)(bd[15] >> 32);                                         \
    }                                                                          \
  }

// Bitonic merge for DISJOINT sorted lists (first merges; keys unique).
#define BMERGE_STEP(MASK)                                                      \
  {                                                                            \
    unsigned long long tmp[16];                                                \
    _Pragma("unroll")                                                          \
    for (int j = 0; j < 16; ++j) tmp[j] = __shfl_xor(bd[15-j], MASK);          \
    _Pragma("unroll")                                                          \
    for (int j = 0; j < 16; ++j) bd[j] = U64MIN(bd[j], tmp[j]);                \
    _Pragma("unroll")                                                          \
    for (int dd2 = 8; dd2 >= 1; dd2 >>= 1) {                                   \
      _Pragma("unroll")                                                        \
      for (int i2 = 0; i2 < 16; ++i2) {                                        \
        if ((i2 & dd2) == 0) {                                                 \
          unsigned long long a2 = bd[i2], b2 = bd[i2 + dd2];                   \
          bd[i2] = U64MIN(a2, b2); bd[i2 + dd2] = U64MAX(a2, b2);              \
        }                                                                      \
      }                                                                        \
    }                                                                          \
    hi15 = (unsigned)(bd[15] >> 32);                                           \
  }

// Dedup butterfly merge for ring re-merges (shared base).
#define MERGE_STEP(MASK)                                                       \
  {                                                                            \
    unsigned long long tmp[16];                                                \
    _Pragma("unroll")                                                          \
    for (int j = 0; j < 16; ++j) tmp[j] = __shfl_xor(bd[j], MASK);             \
    _Pragma("unroll")                                                          \
    for (int j = 0; j < 16; ++j) {                                             \
      unsigned long long _in = tmp[j];                                         \
      bool dup = false;                                                        \
      _Pragma("unroll")                                                        \
      for (int jj = 0; jj < 16; ++jj) dup = dup || (bd[jj] == _in);            \
      INS64(dup ? ~0ull : _in);                                                \
    }                                                                          \
    hi15 = (unsigned)(bd[15] >> 32);                                           \
  }

// knn_query (R14): 16 queries x 4 slices; GRP=3 query-group blocks per cell;
// staged r=1 box; FIFO-batched inserts; O(k) bitonic first merge.
__global__ __launch_bounds__(64) void knn_query_kernel(
    const float4* __restrict__ spts, const int* __restrict__ cellstart,
    int* __restrict__ idx) {
  __shared__ __align__(16) float4 s_cand[CAP];
  __shared__ int s_ofs[28];
  __shared__ int s_jlo[27];
  int wave = blockIdx.x / GRP;
  int g = blockIdx.x % GRP;
  int b = wave >> 9;
  int cell = wave & 511;
  int cx = cell >> 6, cy = (cell >> 3) & 7, cz = cell & 7;
  int cb = b << 9;
  int qlo = cellstart[cb + cell], qhi = cellstart[cb + cell + 1];
  int nq = qhi - qlo;
  if (nq <= 0 || 16*g >= nq) return;
  int lane = threadIdx.x;
  int q = lane & 15, s = lane >> 4;

  int x0 = max(cx-1,0), x1 = min(cx+1,7);
  int y0 = max(cy-1,0), y1 = min(cy+1,7);
  int z0 = max(cz-1,0), z1 = min(cz+1,7);
  int dy = y1-y0+1, dz = z1-z0+1;
  int count = (x1-x0+1)*dy*dz;
  int len = 0, jlo0 = 0;
  if (lane < count) {
    int xx = x0 + lane/(dy*dz);
    int rem = lane % (dy*dz);
    int yy = y0 + rem/dz, zz = z0 + rem % dz;
    int cc = cb + (xx<<6) + (yy<<3) + zz;
    jlo0 = cellstart[cc];
    len = cellstart[cc+1] - jlo0;
  }
  int pre = len;
#pragma unroll
  for (int off = 1; off < 64; off <<= 1) {
    int v = __shfl_up(pre, off);
    if (lane >= off) pre += v;
  }
  if (lane < count) { s_ofs[lane] = pre - len; s_jlo[lane] = jlo0; }
  if (lane == count-1) s_ofs[count] = pre;
  __syncthreads();
  int total = s_ofs[count];
  int tstag = min(total, CAP);

  for (int w = lane; w < tstag; w += 64) {
    int lo2 = 0, hi2 = count-1;
    while (lo2 < hi2) { int mid = (lo2+hi2+1)>>1; if (s_ofs[mid] <= w) lo2 = mid; else hi2 = mid-1; }
    s_cand[w] = spts[s_jlo[lo2] + (w - s_ofs[lo2])];
  }
  __syncthreads();

  const unsigned thru1 = ord32((GCS - 1e-4f)*(GCS - 1e-4f));
  for (int qg = 16*g; qg < nq; qg += 16*GRP) {
    bool valid = (qg + q) < nq;
    float4 qv = spts[qlo + qg + (valid ? q : 0)];
    float qx = qv.x, qy = qv.y, qz = qv.z;
    float qs = qx*qx + qy*qy + qz*qz;
    unsigned long long bd[16];
#pragma unroll
    for (int j = 0; j < 16; ++j) bd[j] = ~0ull;
    unsigned long long fd[4] = {0,0,0,0};
    int fcnt = 0;
    unsigned hi15 = 0xFFFFFFFFu;

    int chunk = (tstag + 3) >> 2;
    int jb = s*chunk, je = min(jb+chunk, tstag);
    for (int j = jb; j < je; ++j) {
      float4 c4 = s_cand[j];
      TRYKEY_F(c4);
    }
    if (__any(fcnt > 0)) { DRAIN64(); }
    if (total > CAP) {
      for (int i = 0; i < count; ++i) {
        int ofs_i = s_ofs[i], len_i = s_ofs[i+1]-ofs_i;
        int stg = min(max(CAP - ofs_i, 0), len_i);
        int jl = s_jlo[i] + stg, jh = s_jlo[i] + len_i;
        for (int j2 = jl + s; j2 < jh; j2 += 4) {
          float4 c4 = spts[j2];
          TRYKEY(c4);
        }
      }
    }
    BMERGE_STEP(16);
    BMERGE_STEP(32);
    bool done = !valid || (hi15 < thru1);
    for (int r = 2; r <= 8; ++r) {
      if (!__any(!done)) break;
      int xs0 = max(cx-r,0), xs1 = min(cx+r,7);
      int ys0 = max(cy-r,0), ys1 = min(cy+r,7);
      int zs0 = max(cz-r,0), zs1 = min(cz+r,7);
      int pr = r-1;
      for (int xx = xs0; xx <= xs1; ++xx)
      for (int yy = ys0; yy <= ys1; ++yy)
      for (int zz = zs0; zz <= zs1; ++zz) {
        if (xx >= cx-pr && xx <= cx+pr && yy >= cy-pr && yy <= cy+pr &&
            zz >= cz-pr && zz <= cz+pr) continue;
        int cc2 = cb + (xx<<6) + (yy<<3) + zz;
        int jl = cellstart[cc2], jh = cellstart[cc2+1];
        for (int j2 = jl + s; j2 < jh; j2 += 4) {
          float4 c4 = spts[j2];
          TRYKEY(c4);
        }
      }
      MERGE_STEP(16);
      MERGE_STEP(32);
      float thr2 = (float)r * GCS - 1e-4f;
      done = !valid || (hi15 < ord32(thr2*thr2));
    }
    if (valid && s == 0) {
      int n_self = __float_as_int(qv.w);
      int* op = idx + (((long)b << 13) + n_self) * 16;
#pragma unroll
      for (int j = 0; j < 16; ++j) op[j] = (int)(unsigned)(bd[j] & 0xffffffffu);
    }
  }
}

// ---------------- fused FKAConv v5: 256 thr = 4 waves = 4 points ----------------
// + next-layer xproj fused into the epilogue (c_new staged in LDS; x is
// double-buffered so in-flight readers of x(l) never race the x(l+1) writes).
#define OFF_W1   0
#define OFF_W2AT 48
#define OFF_W2BT 368
#define OFF_W3AT 688
#define OFF_W3BT 1008
#define OFF_B2   1328      // [64]
#define OFF_RED  1392      // y partials [8 seg][4 pt][32 o]
#define OFF_Y    2416      // [4 pt][32 o]
#define OFF_CN   2544      // c_new [4 pt][64]
#define OFF_SCR  2800      // per-wave scratch x4
#define SCR_SZ   1296
#define S_DW 0
#define S_M1 16
#define S_M2 272
#define S_MM 528
#define S_XN 784
#define S_FB 16            // overlays M1+M2 (dead after stage C)
#define LDS_TOT (OFF_SCR + 4*SCR_SZ)   // 7984 floats = 31936 B -> 5 blocks/CU

__global__ __launch_bounds__(256) void conv_kernel(
    float* __restrict__ c, const float* __restrict__ xin,
    float* __restrict__ xout,
    const int* __restrict__ idx, const float* __restrict__ xyz,
    const float* __restrict__ fc1, const float* __restrict__ fc2,
    const float* __restrict__ fc3, const float* __restrict__ wcv,
    const float* __restrict__ alpha, const float* __restrict__ beta,
    const float* __restrict__ w2, const float* __restrict__ b2,
    const float* __restrict__ w0, const float* __restrict__ b0, int layer)
{
  __shared__ __align__(16) float lds[LDS_TOT];
  int t = threadIdx.x;

  const float* fc1l = fc1 + layer*3*KK;
  const float* fc2l = fc2 + layer*2*KK*KK;
  const float* fc3l = fc3 + layer*2*KK*KK;
  const float* wcvl = wcv + layer*HH*HH*KK;
  const float* w2l  = w2  + layer*HH*DIMM;
  const float* b2l  = b2  + layer*DIMM;
  bool do_x = (layer + 1) < NBB;
  const float* w0n = w0 + (layer+1)*DIMM*HH;
  const float* b0n = b0 + (layer+1)*HH;

  if (t < 48) lds[OFF_W1 + t] = fc1l[t];
  {
    int s = t >> 4, tt = t & 15;
    lds[OFF_W2AT + s*20 + tt] = fc2l[tt*16 + s];
    lds[OFF_W2BT + s*20 + tt] = fc2l[(16+tt)*16 + s];
    lds[OFF_W3AT + s*20 + tt] = fc3l[tt*16 + s];
    lds[OFF_W3BT + s*20 + tt] = fc3l[(16+tt)*16 + s];
  }
  if (t < 64) lds[OFF_B2 + t] = b2l[t];
  __syncthreads();                                  // barrier 1

  int wv = t >> 6, lane = t & 63;
  int p = blockIdx.x*4 + wv;
  int b = p >> 13;
  float* scr = lds + OFF_SCR + wv*SCR_SZ;
  int sI = lane & 15;

  // ---- stage A (per-wave scratch only) ----
  float qxx = xyz[p*3+0], qyy = xyz[p*3+1], qzz = xyz[p*3+2];
  float alv = alpha[layer], bev = beta[layer];
  int jidx = 0; float px = 0, py = 0, pz = 0, sv = 0;
  if (lane < 16) {
    jidx = idx[p*16 + lane];
    const float* nb = xyz + ((long)b*NN + jidx)*3;
    px = nb[0]-qxx; py = nb[1]-qyy; pz = nb[2]-qzz;
    float dd = sqrtf(px*px + py*py + pz*pz + 1e-12f);
    sv = 1.0f/(1.0f + expf(alv*dd - bev));
  }
  float ssum = 0.0f;
#pragma unroll
  for (int k = 0; k < 16; ++k) ssum += __shfl(sv, k);
  if (lane < 16) scr[S_DW + lane] = sv / (ssum + 1e-6f) * 16.0f;
#pragma unroll
  for (int r = 0; r < 2; ++r) {
    int tsk = lane + 64*r;
    int k = tsk >> 3, seg = tsk & 7;
    int jk = __shfl(jidx, k);
    float4 v = *(const float4*)(xin + ((long)b*NN + jk)*32 + seg*4);
    *(float4*)&scr[S_XN + k*32 + seg*4] = v;
  }
#pragma unroll
  for (int r = 0; r < 4; ++r) {
    int k = (lane >> 4) + 4*r;
    float pxk = __shfl(px, k), pyk = __shfl(py, k), pzk = __shfl(pz, k);
    float v = pxk*lds[OFF_W1+sI] + pyk*lds[OFF_W1+16+sI] + pzk*lds[OFF_W1+32+sI];
    scr[S_M1 + k*16 + sI] = fmaxf(v, 0.0f);
  }

  // ---- stage B ----
  {
    float mpv = 0.0f;
#pragma unroll
    for (int k = 0; k < 16; ++k) mpv = fmaxf(mpv, scr[S_M1 + k*16 + sI] * scr[S_DW + k]);
    float qv = 0.0f;
#pragma unroll
    for (int tt = 0; tt < 16; ++tt) qv += __shfl(mpv, tt) * lds[OFF_W2BT + sI*20 + tt];
    float4 wa0 = *(float4*)&lds[OFF_W2AT + sI*20 + 0];
    float4 wa1 = *(float4*)&lds[OFF_W2AT + sI*20 + 4];
    float4 wa2 = *(float4*)&lds[OFF_W2AT + sI*20 + 8];
    float4 wa3 = *(float4*)&lds[OFF_W2AT + sI*20 + 12];
#pragma unroll
    for (int r = 0; r < 4; ++r) {
      int k = (lane >> 4) + 4*r;
      float4 m0 = *(float4*)&scr[S_M1 + k*16 + 0];
      float4 m1_ = *(float4*)&scr[S_M1 + k*16 + 4];
      float4 m2_ = *(float4*)&scr[S_M1 + k*16 + 8];
      float4 m3_ = *(float4*)&scr[S_M1 + k*16 + 12];
      float v = qv;
      v += m0.x*wa0.x; v += m0.y*wa0.y; v += m0.z*wa0.z; v += m0.w*wa0.w;
      v += m1_.x*wa1.x; v += m1_.y*wa1.y; v += m1_.z*wa1.z; v += m1_.w*wa1.w;
      v += m2_.x*wa2.x; v += m2_.y*wa2.y; v += m2_.z*wa2.z; v += m2_.w*wa2.w;
      v += m3_.x*wa3.x; v += m3_.y*wa3.y; v += m3_.z*wa3.z; v += m3_.w*wa3.w;
      scr[S_M2 + k*16 + sI] = fmaxf(v, 0.0f);
    }
  }

  // ---- stage C ----
  {
    float mpv = 0.0f;
#pragma unroll
    for (int k = 0; k < 16; ++k) mpv = fmaxf(mpv, scr[S_M2 + k*16 + sI] * scr[S_DW + k]);
    float qv = 0.0f;
#pragma unroll
    for (int tt = 0; tt < 16; ++tt) qv += __shfl(mpv, tt) * lds[OFF_W3BT + sI*20 + tt];
    float4 wa0 = *(float4*)&lds[OFF_W3AT + sI*20 + 0];
    float4 wa1 = *(float4*)&lds[OFF_W3AT + sI*20 + 4];
    float4 wa2 = *(float4*)&lds[OFF_W3AT + sI*20 + 8];
    float4 wa3 = *(float4*)&lds[OFF_W3AT + sI*20 + 12];
#pragma unroll
    for (int r = 0; r < 4; ++r) {
      int k = (lane >> 4) + 4*r;
      float4 m0 = *(float4*)&scr[S_M2 + k*16 + 0];
      float4 m1_ = *(float4*)&scr[S_M2 + k*16 + 4];
      float4 m2_ = *(float4*)&scr[S_M2 + k*16 + 8];
      float4 m3_ = *(float4*)&scr[S_M2 + k*16 + 12];
      float v = qv;
      v += m0.x*wa0.x; v += m0.y*wa0.y; v += m0.z*wa0.z; v += m0.w*wa0.w;
      v += m1_.x*wa1.x; v += m1_.y*wa1.y; v += m1_.z*wa1.z; v += m1_.w*wa1.w;
      v += m2_.x*wa2.x; v += m2_.y*wa2.y; v += m2_.z*wa2.z; v += m2_.w*wa2.w;
      v += m3_.x*wa3.x; v += m3_.y*wa3.y; v += m3_.z*wa3.z; v += m3_.w*wa3.w;
      scr[S_MM + k*16 + sI] = fmaxf(v, 0.0f) * scr[S_DW + k];
    }
  }

  // ---- stage D: f[c][s] into FB (overlays dead M1+M2) ----
  {
    int q4 = lane >> 4;
    float fr0=0,fr1=0,fr2=0,fr3=0,fr4=0,fr5=0,fr6=0,fr7=0;
#pragma unroll
    for (int k = 0; k < 16; ++k) {
      float mmv = scr[S_MM + k*16 + sI];
      float4 a  = *(float4*)&scr[S_XN + k*32 + q4*8];
      float4 bb = *(float4*)&scr[S_XN + k*32 + q4*8 + 4];
      fr0 += a.x*mmv;  fr1 += a.y*mmv;  fr2 += a.z*mmv;  fr3 += a.w*mmv;
      fr4 += bb.x*mmv; fr5 += bb.y*mmv; fr6 += bb.z*mmv; fr7 += bb.w*mmv;
    }
    scr[S_FB + (q4*8+0)*16 + sI] = fr0;
    scr[S_FB + (q4*8+1)*16 + sI] = fr1;
    scr[S_FB + (q4*8+2)*16 + sI] = fr2;
    scr[S_FB + (q4*8+3)*16 + sI] = fr3;
    scr[S_FB + (q4*8+4)*16 + sI] = fr4;
    scr[S_FB + (q4*8+5)*16 + sI] = fr5;
    scr[S_FB + (q4*8+6)*16 + sI] = fr6;
    scr[S_FB + (q4*8+7)*16 + sI] = fr7;
  }
  __syncthreads();                                  // barrier 2 (cross-wave FB)

  // ---- block GEMM y-einsum ----
  {
    int o = t & 31, seg = t >> 5;
    const float4* wrow = (const float4*)(wcvl + o*512 + seg*64);
    float acc0=0, acc1=0, acc2=0, acc3=0;
#pragma unroll
    for (int j = 0; j < 16; ++j) {
      float4 w4 = wrow[j];
      float4 f0 = *(const float4*)&lds[OFF_SCR + 0*SCR_SZ + S_FB + seg*64 + j*4];
      float4 f1 = *(const float4*)&lds[OFF_SCR + 1*SCR_SZ + S_FB + seg*64 + j*4];
      float4 f2 = *(const float4*)&lds[OFF_SCR + 2*SCR_SZ + S_FB + seg*64 + j*4];
      float4 f3 = *(const float4*)&lds[OFF_SCR + 3*SCR_SZ + S_FB + seg*64 + j*4];
      acc0 += w4.x*f0.x; acc0 += w4.y*f0.y; acc0 += w4.z*f0.z; acc0 += w4.w*f0.w;
      acc1 += w4.x*f1.x; acc1 += w4.y*f1.y; acc1 += w4.z*f1.z; acc1 += w4.w*f1.w;
      acc2 += w4.x*f2.x; acc2 += w4.y*f2.y; acc2 += w4.z*f2.z; acc2 += w4.w*f2.w;
      acc3 += w4.x*f3.x; acc3 += w4.y*f3.y; acc3 += w4.z*f3.z; acc3 += w4.w*f3.w;
    }
    lds[OFF_RED + seg*128 + 0*32 + o] = acc0;
    lds[OFF_RED + seg*128 + 1*32 + o] = acc1;
    lds[OFF_RED + seg*128 + 2*32 + o] = acc2;
    lds[OFF_RED + seg*128 + 3*32 + o] = acc3;
  }
  __syncthreads();                                  // barrier 3

  if (t < 128) {
    int pt = t >> 5, o = t & 31;
    float yv = 0.0f;
#pragma unroll
    for (int seg = 0; seg < 8; ++seg) yv += lds[OFF_RED + seg*128 + pt*32 + o];
    lds[OFF_Y + pt*32 + o] = fmaxf(yv, 0.0f);
  }
  __syncthreads();                                  // barrier 4

  // ---- final: c = relu(y @ w2 + b2 + c); stash c_new in LDS for fused xproj ----
  {
    int pt = t >> 6, d = t & 63;
    float zv = lds[OFF_B2 + d];
    const float* w2g = w2l + d;
#pragma unroll
    for (int o = 0; o < 32; ++o) zv += lds[OFF_Y + pt*32 + o] * w2g[o*64];
    int gp = blockIdx.x*4 + pt;
    float cv = c[gp*64 + d];
    float cnew = fmaxf(zv + cv, 0.0f);
    c[gp*64 + d] = cnew;
    lds[OFF_CN + pt*64 + d] = cnew;
  }
  if (do_x) {
    __syncthreads();                                // barrier 5
    if (t < 128) {
      int pt = t >> 5, h = t & 31;
      float acc = b0n[h];
#pragma unroll
      for (int d = 0; d < DIMM; ++d) acc += lds[OFF_CN + pt*64 + d] * w0n[d*HH + h];
      int gp = blockIdx.x*4 + pt;
      xout[gp*HH + h] = fmaxf(acc, 0.0f);
    }
  }
}

// ---------------- triplane scatter-accumulate ----------------
__global__ void triacc_kernel(const float* __restrict__ c,
                              const float* __restrict__ xyz,
                              float* __restrict__ psum,
                              float* __restrict__ pcnt) {
  int tid = blockIdx.x * blockDim.x + threadIdx.x;
  if (tid >= NPTS*DIMM) return;
  int p = tid >> 6, d = tid & 63;
  int b = p >> 13;
  float p0 = xyz[p*3+0] / 1.101f + 0.5f;
  float p1 = xyz[p*3+1] / 1.101f + 0.5f;
  float p2 = xyz[p*3+2] / 1.101f + 0.5f;
  int i0 = min(max((int)(p0*64.0f), 0), 63);
  int i1 = min(max((int)(p1*64.0f), 0), 63);
  int i2 = min(max((int)(p2*64.0f), 0), 63);
  int cb = b*3*RESS*RESS;
  int c0 = cb + 0*RESS*RESS + i0*RESS + i1;
  int c1 = cb + 1*RESS*RESS + i0*RESS + i2;
  int c2 = cb + 2*RESS*RESS + i1*RESS + i2;
  float v = c[tid];
  atomicAdd(&psum[c0*DIMM + d], v);
  atomicAdd(&psum[c1*DIMM + d], v);
  atomicAdd(&psum[c2*DIMM + d], v);
  if (d == 0) {
    atomicAdd(&pcnt[c0], 1.0f);
    atomicAdd(&pcnt[c1], 1.0f);
    atomicAdd(&pcnt[c2], 1.0f);
  }
}

// ---------------- triplane normalize ----------------
__global__ void trinorm_kernel(const float* __restrict__ psum,
                               const float* __restrict__ pcnt,
                               float* __restrict__ out) {
  int tid = blockIdx.x * blockDim.x + threadIdx.x;
  if (tid >= PLANE_ELEMS) return;
  float cnt = pcnt[tid >> 6];
  out[tid] = psum[tid] / fmaxf(cnt, 1.0f);
}

extern "C" void kernel_launch(void* const* d_in, const int* in_sizes, int n_in,
                              void* d_out, int out_size, void* d_ws, size_t ws_size,
                              hipStream_t stream) {
  const float* xyz   = (const float*)d_in[0];
  const float* wstem = (const float*)d_in[1];
  const float* bstem = (const float*)d_in[2];
  const float* w0    = (const float*)d_in[3];
  const float* b0    = (const float*)d_in[4];
  const float* fc1   = (const float*)d_in[5];
  const float* fc2   = (const float*)d_in[6];
  const float* fc3   = (const float*)d_in[7];
  const float* wcv   = (const float*)d_in[8];
  const float* alpha = (const float*)d_in[9];
  const float* beta  = (const float*)d_in[10];
  const float* w2    = (const float*)d_in[11];
  const float* b2    = (const float*)d_in[12];

  float* out     = (float*)d_out;
  float* out_xyz = out;                       // 49152
  float* c       = out + NPTS*3;              // working c buffer
  float* out_tri = c + NPTS*DIMM;             // 1572864

  float* wsf  = (float*)d_ws;
  int*   idx  = (int*)d_ws;                   // NPTS*16 int32
  float* xA   = wsf + NPTS*16;                // NPTS*32
  float* psum = xA + NPTS*HH;                 // PLANE_ELEMS
  float* pcnt = psum + PLANE_ELEMS;           // PLANE_CELLS

  // knn arrays + xB ALIAS psum (dead until triplane; re-zeroed before triacc)
  int*    cellcnt   = (int*)psum;             // 1024
  int*    cellstart = (int*)psum + 1024;      // 1025 (pad to 1032)
  int*    cellcur   = (int*)psum + 2056;      // 1024
  float4* spts      = (float4*)(psum + 4096); // 16384 float4 (65536 floats)
  float*  xB        = psum + 69632;           // NPTS*32 floats (aliases psum)

  zero_kernel<<<4, 256, 0, stream>>>((float*)cellcnt, 1024);
  stem_kernel<<<(NPTS*DIMM+255)/256, 256, 0, stream>>>(
      xyz, wstem, bstem, w0, b0, out_xyz, c, xA, cellcnt);
  knn_scan_kernel<<<1, 1024, 0, stream>>>(cellcnt, cellstart, cellcur);
  knn_scatter_kernel<<<(NPTS+255)/256, 256, 0, stream>>>(xyz, cellcur, spts);
  knn_query_kernel<<<1024*GRP, 64, 0, stream>>>(spts, cellstart, idx);
  for (int layer = 0; layer < NBB; ++layer) {
    float* xin  = (layer & 1) ? xB : xA;
    float* xout = (layer & 1) ? xA : xB;
    conv_kernel<<<NPTS/4, 256, 0, stream>>>(c, xin, xout, idx, xyz,
                                            fc1, fc2, fc3, wcv, alpha, beta,
                                            w2, b2, w0, b0, layer);
  }
  int nz = PLANE_ELEMS + PLANE_CELLS;
  zero_kernel<<<(nz+255)/256, 256, 0, stream>>>(psum, nz);
  triacc_kernel<<<(NPTS*DIMM+255)/256, 256, 0, stream>>>(c, xyz, psum, pcnt);
  trinorm_kernel<<<(PLANE_ELEMS+255)/256, 256, 0, stream>>>(psum, pcnt, out_tri);
}